// Round 1
// 728.649 us; speedup vs baseline: 1.2751x; 1.2751x over previous
//
#include <hip/hip_runtime.h>
#include <hip/hip_bf16.h>
#include <string.h>

typedef unsigned short u16;
typedef __attribute__((ext_vector_type(8))) short short8;
typedef __attribute__((ext_vector_type(4))) float floatx4;
typedef __attribute__((ext_vector_type(4))) unsigned short ushort4v;
typedef __attribute__((ext_vector_type(8))) unsigned short ushort8v;
typedef __attribute__((ext_vector_type(2))) unsigned int uint2v;

#define NWIN 2048
#define NTOK 49
#define NH 16
#define HDIM 32
#define CDIM 512
#define MTOT (NWIN * NTOK)   /* 100352 */
#define NOUT (3 * CDIM)      /* 1536 */
#define KDIM CDIM            /* 512 */

__device__ inline float b2f(u16 u) {
    unsigned int x = ((unsigned int)u) << 16;
    float f; __builtin_memcpy(&f, &x, 4); return f;
}
__device__ inline u16 f2b(float f) {
    unsigned int u; __builtin_memcpy(&u, &f, 4);
    unsigned int r = (u + 0x7fffu + ((u >> 16) & 1u)) >> 16;
    return (u16)r;
}
__device__ inline void gload16(const void* g, void* l) {
    __builtin_amdgcn_global_load_lds((const __attribute__((address_space(1))) unsigned int*)g,
                                     (__attribute__((address_space(3))) unsigned int*)l, 16, 0, 0);
}

// ---------------- prep: fp32 -> bf16 convert of hidden_states ----------------
__global__ void k_cvt_x(const float4* __restrict__ x, ushort4v* __restrict__ xb, int n4) {
    int i = blockIdx.x * blockDim.x + threadIdx.x;
    int stride = gridDim.x * blockDim.x;
    for (; i < n4; i += stride) {
        float4 v = x[i];
        ushort4v o = { f2b(v.x), f2b(v.y), f2b(v.z), f2b(v.w) };
        xb[i] = o;
    }
}

// ---------------- prep: pack Wqkv (bf16 [1536,512]) + bias (fp32 [1536]) -----
__global__ void k_pack_w(const float* __restrict__ wq, const float* __restrict__ wk,
                         const float* __restrict__ wv, const float* __restrict__ bq,
                         const float* __restrict__ bk, const float* __restrict__ bv,
                         u16* __restrict__ wout, float* __restrict__ bout) {
    const int WN = CDIM * CDIM; // 262144
    int i = blockIdx.x * blockDim.x + threadIdx.x;
    if (i < 3 * WN) {
        const float* src = (i < WN) ? wq : (i < 2 * WN ? wk : wv);
        wout[i] = f2b(src[i & (WN - 1)]);
    }
    if (i < 3 * CDIM) {
        const float* sb = (i < CDIM) ? bq : (i < 2 * CDIM ? bk : bv);
        bout[i] = sb[i & (CDIM - 1)];
    }
}

// ---------------- prep: bias+mask table, KEY-MAJOR: bmT[w][h][j][i] ----------
// (transposed vs reference so k_attn's per-score loads are coalesced along i)
__global__ void k_bm(const float* __restrict__ mask, const float* __restrict__ bt,
                     float* __restrict__ bm) {
    int t = blockIdx.x;          // 0..1023
    int w = t >> 4, h = t & 15;
    for (int e = threadIdx.x; e < NTOK * NTOK; e += blockDim.x) {
        int j = e / 49, i = e - j * 49;          // j = key (slow), i = query (fast)
        int ri = i / 7, ci = i - ri * 7;
        int rj = j / 7, cj = j - rj * 7;
        int idx = (ri - rj + 6) * 13 + (ci - cj + 6);
        bm[(size_t)t * 2401 + e] = bt[idx * 16 + h] + mask[(size_t)w * 2401 + i * 49 + j];
    }
}

// ---------------- QKV projection GEMM: [100352,512] x [1536,512]^T -----------
// 128x128 tile, BK=32, 4 waves (2x2 of 64x64), global_load_lds w16,
// XOR-swizzled LDS chunks so ds_read_b128 fragment reads are 2-way (free).
__global__ __launch_bounds__(256)
void k_gemm(const u16* __restrict__ A, const u16* __restrict__ Bw,
            const float* __restrict__ bias, u16* __restrict__ C) {
    __shared__ __align__(16) u16 As[128 * 32];
    __shared__ __align__(16) u16 Bs[128 * 32];
    const int tid = threadIdx.x;
    const int lane = tid & 63;
    const int wave = tid >> 6;
    const int n0 = blockIdx.x * 128;   // x fastest: 12 n-tiles share an A-tile in L2
    const int m0 = blockIdx.y * 128;
    const int mh = (wave & 1) * 64;
    const int nh = (wave >> 1) * 64;

    floatx4 acc[4][4];
#pragma unroll
    for (int mi = 0; mi < 4; mi++)
#pragma unroll
        for (int ni = 0; ni < 4; ni++)
            acc[mi][ni] = (floatx4){0.f, 0.f, 0.f, 0.f};

    // staging: 512 x 16B per tile per matrix; thread does i and i+256
    const int rA1 = tid >> 2, c1 = tid & 3;
    const int rA2 = rA1 + 64;
    const int cg1 = c1 ^ ((rA1 >> 1) & 3);
    const int cg2 = c1 ^ ((rA2 >> 1) & 3);
    const u16* pa1 = A + (size_t)(m0 + rA1) * KDIM + cg1 * 8;
    const u16* pa2 = A + (size_t)(m0 + rA2) * KDIM + cg2 * 8;
    const u16* pb1 = Bw + (size_t)(n0 + rA1) * KDIM + cg1 * 8;
    const u16* pb2 = Bw + (size_t)(n0 + rA2) * KDIM + cg2 * 8;
    u16* la1 = &As[tid * 8];
    u16* la2 = &As[(tid + 256) * 8];
    u16* lb1 = &Bs[tid * 8];
    u16* lb2 = &Bs[(tid + 256) * 8];

    // fragment LDS offsets (elements): row r, chunk = quad ^ ((r>>1)&3)
    int aoff[4], boff[4];
    const int quad = lane >> 4;
#pragma unroll
    for (int mi = 0; mi < 4; mi++) {
        int r = mh + mi * 16 + (lane & 15);
        aoff[mi] = r * 32 + (quad ^ ((r >> 1) & 3)) * 8;
        int rn = nh + mi * 16 + (lane & 15);
        boff[mi] = rn * 32 + (quad ^ ((rn >> 1) & 3)) * 8;
    }

    for (int ks = 0; ks < 16; ++ks) {
        const int k0 = ks * 32;
        gload16(pa1 + k0, la1);
        gload16(pa2 + k0, la2);
        gload16(pb1 + k0, lb1);
        gload16(pb2 + k0, lb2);
        __syncthreads();
        short8 af[4], bf[4];
#pragma unroll
        for (int mi = 0; mi < 4; mi++) af[mi] = *(const short8*)&As[aoff[mi]];
#pragma unroll
        for (int ni = 0; ni < 4; ni++) bf[ni] = *(const short8*)&Bs[boff[ni]];
#pragma unroll
        for (int mi = 0; mi < 4; mi++)
#pragma unroll
            for (int ni = 0; ni < 4; ni++)
                acc[mi][ni] = __builtin_amdgcn_mfma_f32_16x16x32_bf16(af[mi], bf[ni], acc[mi][ni], 0, 0, 0);
        __syncthreads();
    }

    // epilogue: D row=(quad*4+r), col=(lane&15); add bias, store bf16
    const int colc = lane & 15;
#pragma unroll
    for (int ni = 0; ni < 4; ni++) {
        int gn = n0 + nh + ni * 16 + colc;
        float bv_ = bias[gn];
#pragma unroll
        for (int mi = 0; mi < 4; mi++) {
            size_t gmb = (size_t)(m0 + mh + mi * 16 + quad * 4);
#pragma unroll
            for (int r = 0; r < 4; r++)
                C[(gmb + r) * NOUT + gn] = f2b(acc[mi][ni][r] + bv_);
        }
    }
}

// ---------------- attention: MFMA, one wave per (window b, head h) -----------
// S^T = mfma(K, Q) (row=j key, col=i query) so softmax over j is 16 in-lane
// values + 2 shfl_xor. P normalized in-register, bf16, XOR-swizzled LDS
// round-trip; PV = mfma(P, V) with V staged swizzled in LDS. No barriers:
// LDS is wave-private (waits via lgkmcnt only).
__global__ __launch_bounds__(256, 3)
void k_attn(const u16* __restrict__ qkv, const float* __restrict__ bmT,
            float* __restrict__ out) {
    __shared__ __align__(16) char smem[4 * 12288];  // per wave: V 4KB + P 8KB
    const int lane = threadIdx.x & 63;
    const int wave = threadIdx.x >> 6;
    const int task = blockIdx.x * 4 + wave;  // 0..32767
    const int b = task >> 4;
    const int h = task & 15;
    const int c = lane & 15;
    const int quad = lane >> 4;
    char* Vs = smem + wave * 12288;
    char* Ps = Vs + 4096;

    const u16* qbase = qkv + (size_t)b * NTOK * NOUT + h * 32;

    // ---- Q/K fragments direct from global (A/B frag = 16 contiguous bytes) ----
    short8 kf[4], qf[4];
#pragma unroll
    for (int mi = 0; mi < 4; mi++) {
        int jr = mi * 16 + c; jr = jr > 48 ? 48 : jr;
        kf[mi] = *(const short8*)(qbase + (size_t)jr * NOUT + 512 + quad * 8);
    }
#pragma unroll
    for (int ni = 0; ni < 4; ni++) {
        int ir = ni * 16 + c; ir = ir > 48 ? 48 : ir;
        qf[ni] = *(const short8*)(qbase + (size_t)ir * NOUT + quad * 8);
    }

    // ---- stage V -> LDS bf16 [64 rows][32 d], 16B-slot swizzle, pad rows = 0 ----
#pragma unroll
    for (int it = 0; it < 4; it++) {
        int j = it * 16 + (lane >> 2);
        int part = lane & 3;
        ushort8v val = {0, 0, 0, 0, 0, 0, 0, 0};
        if (j < 49) val = *(const ushort8v*)(qbase + (size_t)j * NOUT + 1024 + part * 8);
        int byt = (j * 64 + part * 16) ^ (((j >> 3) & 3) << 4);
        *(ushort8v*)(Vs + byt) = val;
    }

    // ---- S^T = K @ Q^T: acc[mi][ni], row j = mi*16+quad*4+r, col i = ni*16+c ----
    floatx4 acc[4][4];
#pragma unroll
    for (int mi = 0; mi < 4; mi++)
#pragma unroll
        for (int ni = 0; ni < 4; ni++)
            acc[mi][ni] = (floatx4){0.f, 0.f, 0.f, 0.f};
#pragma unroll
    for (int mi = 0; mi < 4; mi++)
#pragma unroll
        for (int ni = 0; ni < 4; ni++)
            acc[mi][ni] = __builtin_amdgcn_mfma_f32_16x16x32_bf16(kf[mi], qf[ni], acc[mi][ni], 0, 0, 0);

    // ---- scale + (bias+mask), key-major table: bmT[.. + j*49 + i] ----
    const float scale = 0.17677669529663687f;
    const float* bmrow = bmT + ((size_t)((b & 63) * 16 + h)) * 2401;
#pragma unroll
    for (int mi = 0; mi < 4; mi++)
#pragma unroll
        for (int r = 0; r < 4; r++) {
            int j = mi * 16 + quad * 4 + r;
            int jc = j > 48 ? 48 : j;
            const float* bp = bmrow + jc * 49;
#pragma unroll
            for (int ni = 0; ni < 4; ni++) {
                int i = ni * 16 + c;
                int ic = i > 48 ? 48 : i;
                acc[mi][ni][r] = acc[mi][ni][r] * scale + bp[ic];
            }
        }

    // ---- softmax over j per column i: in-lane 13 valid + shfl_xor(16,32) ----
#pragma unroll
    for (int ni = 0; ni < 4; ni++) {
        float mx = -3.0e38f;
#pragma unroll
        for (int mi = 0; mi < 3; mi++)
#pragma unroll
            for (int r = 0; r < 4; r++) mx = fmaxf(mx, acc[mi][ni][r]);
        if (quad == 0) mx = fmaxf(mx, acc[3][ni][0]);   // j == 48
        mx = fmaxf(mx, __shfl_xor(mx, 16));
        mx = fmaxf(mx, __shfl_xor(mx, 32));
        float sum = 0.f;
#pragma unroll
        for (int mi = 0; mi < 3; mi++)
#pragma unroll
            for (int r = 0; r < 4; r++) {
                float e = __expf(acc[mi][ni][r] - mx);
                acc[mi][ni][r] = e; sum += e;
            }
        float e0 = (quad == 0) ? __expf(acc[3][ni][0] - mx) : 0.f;
        acc[3][ni][0] = e0; sum += e0;
        acc[3][ni][1] = 0.f; acc[3][ni][2] = 0.f; acc[3][ni][3] = 0.f;
        sum += __shfl_xor(sum, 16);
        sum += __shfl_xor(sum, 32);
        float inv = 1.0f / sum;
#pragma unroll
        for (int mi = 0; mi < 4; mi++)
#pragma unroll
            for (int r = 0; r < 4; r++) acc[mi][ni][r] *= inv;
    }

    // ---- write P[i][j] bf16 to LDS, byte(i,j) = i*128 + (j*2 ^ ((i&7)<<4)) ----
    const int cx = (c & 7) << 4;
#pragma unroll
    for (int ni = 0; ni < 4; ni++) {
        char* prow = Ps + (ni * 16 + c) * 128;
#pragma unroll
        for (int mi = 0; mi < 4; mi++) {
            unsigned int d0, d1;
            asm("v_cvt_pk_bf16_f32 %0, %1, %2" : "=v"(d0) : "v"(acc[mi][ni][0]), "v"(acc[mi][ni][1]));
            asm("v_cvt_pk_bf16_f32 %0, %1, %2" : "=v"(d1) : "v"(acc[mi][ni][2]), "v"(acc[mi][ni][3]));
            uint2v w2 = { d0, d1 };
            *(uint2v*)(prow + ((mi * 32 + quad * 8) ^ cx)) = w2;
        }
    }

    // ---- make all LDS writes (V stage + P) visible to this wave's reads ----
    asm volatile("s_waitcnt lgkmcnt(0)" ::: "memory");

    // ---- ctx = P @ V: A-frag = P rows (swizzled b128), B-frag = V cols ----
    floatx4 acc2[4][2];
#pragma unroll
    for (int mi = 0; mi < 4; mi++)
#pragma unroll
        for (int ni = 0; ni < 2; ni++) acc2[mi][ni] = (floatx4){0.f, 0.f, 0.f, 0.f};
    const int vb0 = quad * 512 + (((0 * 16 + c) * 2) ^ (quad << 4));
    const int vb1 = quad * 512 + (((1 * 16 + c) * 2) ^ (quad << 4));
#pragma unroll
    for (int kk = 0; kk < 2; kk++) {
        const int plow = (kk * 64 + quad * 16) ^ cx;
        short8 pf[4];
#pragma unroll
        for (int mi = 0; mi < 4; mi++)
            pf[mi] = *(const short8*)(Ps + mi * 2048 + c * 128 + plow);
        short8 vf[2];
#pragma unroll
        for (int ni = 0; ni < 2; ni++) {
            const char* vbp = Vs + (ni ? vb1 : vb0) + kk * 2048;
#pragma unroll
            for (int z = 0; z < 8; z++)
                vf[ni][z] = *(const short*)(vbp + z * 64);
        }
#pragma unroll
        for (int mi = 0; mi < 4; mi++)
#pragma unroll
            for (int ni = 0; ni < 2; ni++)
                acc2[mi][ni] = __builtin_amdgcn_mfma_f32_16x16x32_bf16(pf[mi], vf[ni], acc2[mi][ni], 0, 0, 0);
    }

    // ---- store: D row = i = mi*16+quad*4+r, col = d = ni*16+c (fp32 out) ----
    float* ob = out + (size_t)b * 49 * CDIM + h * 32;
#pragma unroll
    for (int mi = 0; mi < 4; mi++)
#pragma unroll
        for (int r = 0; r < 4; r++) {
            int i = mi * 16 + quad * 4 + r;
            if (i < 49) {
                float* orow = ob + (size_t)i * CDIM + c;
#pragma unroll
                for (int ni = 0; ni < 2; ni++)
                    orow[ni * 16] = acc2[mi][ni][r];
            }
        }
}

extern "C" void kernel_launch(void* const* d_in, const int* in_sizes, int n_in,
                              void* d_out, int out_size, void* d_ws, size_t ws_size,
                              hipStream_t stream) {
    const float* hs   = (const float*)d_in[0];
    const float* mask = (const float*)d_in[1];
    const float* wq   = (const float*)d_in[2];
    const float* bq   = (const float*)d_in[3];
    const float* wk   = (const float*)d_in[4];
    const float* bk   = (const float*)d_in[5];
    const float* wv   = (const float*)d_in[6];
    const float* bv   = (const float*)d_in[7];
    const float* bt   = (const float*)d_in[8];
    float* out = (float*)d_out;

    char* ws = (char*)d_ws;
    size_t off = 0;
    u16* xb = (u16*)(ws + off);      off += (size_t)MTOT * CDIM * 2;       // 102.8 MB
    u16* wb = (u16*)(ws + off);      off += (size_t)NOUT * KDIM * 2;       // 1.5 MB
    float* biasb = (float*)(ws + off); off += (size_t)NOUT * 4;
    off = (off + 255) & ~(size_t)255;
    float* bm = (float*)(ws + off);  off += (size_t)1024 * 2401 * 4;       // 9.8 MB
    off = (off + 255) & ~(size_t)255;
    u16* qkv = (u16*)(ws + off);     off += (size_t)MTOT * NOUT * 2;       // 308 MB

    k_cvt_x<<<4096, 256, 0, stream>>>((const float4*)hs, (ushort4v*)xb, MTOT * CDIM / 4);
    k_pack_w<<<3072, 256, 0, stream>>>(wq, wk, wv, bq, bk, bv, wb, biasb);
    k_bm<<<1024, 256, 0, stream>>>(mask, bt, bm);
    k_gemm<<<dim3(12, 784), 256, 0, stream>>>(xb, wb, biasb, qkv);
    k_attn<<<8192, 256, 0, stream>>>(qkv, bm, out);
}

// Round 3
// 648.091 us; speedup vs baseline: 1.4336x; 1.1243x over previous
//
#include <hip/hip_runtime.h>
#include <hip/hip_bf16.h>
#include <string.h>

typedef unsigned short u16;
typedef __attribute__((ext_vector_type(8))) short short8;
typedef __attribute__((ext_vector_type(4))) float floatx4;
typedef __attribute__((ext_vector_type(4))) unsigned short ushort4v;
typedef __attribute__((ext_vector_type(8))) unsigned short ushort8v;
typedef __attribute__((ext_vector_type(2))) unsigned int uint2v;

#define NWIN 2048
#define NTOK 49
#define NH 16
#define HDIM 32
#define CDIM 512
#define MTOT (NWIN * NTOK)   /* 100352 */
#define NOUT (3 * CDIM)      /* 1536 */
#define KDIM CDIM            /* 512 */

__device__ inline float b2f(u16 u) {
    unsigned int x = ((unsigned int)u) << 16;
    float f; __builtin_memcpy(&f, &x, 4); return f;
}
__device__ inline u16 f2b(float f) {
    unsigned int u; __builtin_memcpy(&u, &f, 4);
    unsigned int r = (u + 0x7fffu + ((u >> 16) & 1u)) >> 16;
    return (u16)r;
}
__device__ inline void gload16(const void* g, void* l) {
    __builtin_amdgcn_global_load_lds((const __attribute__((address_space(1))) unsigned int*)g,
                                     (__attribute__((address_space(3))) unsigned int*)l, 16, 0, 0);
}

// ---------------- prep: fp32 -> bf16 convert of hidden_states ----------------
__global__ void k_cvt_x(const float4* __restrict__ x, ushort4v* __restrict__ xb, int n4) {
    int i = blockIdx.x * blockDim.x + threadIdx.x;
    int stride = gridDim.x * blockDim.x;
    for (; i < n4; i += stride) {
        float4 v = x[i];
        ushort4v o = { f2b(v.x), f2b(v.y), f2b(v.z), f2b(v.w) };
        xb[i] = o;
    }
}

// ---------------- prep: pack Wqkv (bf16 [1536,512]) + bias (fp32 [1536]) -----
__global__ void k_pack_w(const float* __restrict__ wq, const float* __restrict__ wk,
                         const float* __restrict__ wv, const float* __restrict__ bq,
                         const float* __restrict__ bk, const float* __restrict__ bv,
                         u16* __restrict__ wout, float* __restrict__ bout) {
    const int WN = CDIM * CDIM; // 262144
    int i = blockIdx.x * blockDim.x + threadIdx.x;
    if (i < 3 * WN) {
        const float* src = (i < WN) ? wq : (i < 2 * WN ? wk : wv);
        wout[i] = f2b(src[i & (WN - 1)]);
    }
    if (i < 3 * CDIM) {
        const float* sb = (i < CDIM) ? bq : (i < 2 * CDIM ? bk : bv);
        bout[i] = sb[i & (CDIM - 1)];
    }
}

// ---------------- prep: bias+mask table, KEY-MAJOR: bmT[w][h][j][i] ----------
__global__ void k_bm(const float* __restrict__ mask, const float* __restrict__ bt,
                     float* __restrict__ bm) {
    int t = blockIdx.x;          // 0..1023
    int w = t >> 4, h = t & 15;
    for (int e = threadIdx.x; e < NTOK * NTOK; e += blockDim.x) {
        int j = e / 49, i = e - j * 49;          // j = key (slow), i = query (fast)
        int ri = i / 7, ci = i - ri * 7;
        int rj = j / 7, cj = j - rj * 7;
        int idx = (ri - rj + 6) * 13 + (ci - cj + 6);
        bm[(size_t)t * 2401 + e] = bt[idx * 16 + h] + mask[(size_t)w * 2401 + i * 49 + j];
    }
}

// ---------------- QKV projection GEMM: 256x256 tile, 8-phase schedule --------
// [100352,512] x [1536,512]^T -> [100352,1536] bf16.
// 8 waves (2M x 4N, each 128x64 out), BK=64, 2 K-tiles per iteration.
// LDS 128KB: 2 buffers x {A0,A1,B0,B1} 16KB halves.
// Stage ledger (race-audited): per-buf last reads A@ph3(MH1)/B@ph2(NH1), so
// stages are B0@ph3, B1+A0@ph4, A1@ph5 (buf0) and B0b@ph7, B1b+A0b+A1b@ph8
// (buf1) -- each region staged >=1 barrier after its last reader.
// vmcnt ledger: ph4 queue = [prevT3:8][B0:2][B1+A0:4] -> vmcnt(6) drains buf1;
// ph8 queue = [T2:8][T3:8] -> vmcnt(8) drains buf0. Never 0 in steady state.
__global__ __launch_bounds__(512, 2)
void k_gemm256(const u16* __restrict__ A, const u16* __restrict__ Bw,
               const float* __restrict__ bias, u16* __restrict__ C) {
    __shared__ __align__(16) u16 lds[65536];   // 128 KiB
    const int tid = threadIdx.x;
    const int lane = tid & 63;
    const int wave = tid >> 6;
    const int wm = wave >> 2;        // 0..1
    const int wn = wave & 3;         // 0..3
    const int c = lane & 15;
    const int quad = lane >> 4;

    // XCD swizzle: 2352 blocks -> 8 chunks of 294 (392 m-panels x 6 n)
    const int wg = blockIdx.x;
    const int swz = (wg & 7) * 294 + (wg >> 3);
    const int m0 = (swz / 6) * 256;
    const int n0 = (swz % 6) * 256;

    // ---------------- staging source pointers (pre-swizzled) ----------------
    const int r1 = tid >> 3;                        // 0..63 (row within 64-group)
    const int cg = ((tid & 7) ^ (r1 & 7)) * 8;      // swizzled k-chunk (elements)
    const int bpr = (r1 & 15) * 4 + (r1 >> 4);      // B column-interleave perm
    const u16* pA00 = A + (size_t)(m0 + r1) * KDIM + cg;
    const u16* pA01 = A + (size_t)(m0 + 64 + r1) * KDIM + cg;
    const u16* pA10 = A + (size_t)(m0 + 128 + r1) * KDIM + cg;
    const u16* pA11 = A + (size_t)(m0 + 192 + r1) * KDIM + cg;
    const u16* pB00 = Bw + (size_t)(n0 + bpr) * KDIM + cg;
    const u16* pB01 = Bw + (size_t)(n0 + 64 + bpr) * KDIM + cg;
    const u16* pB10 = Bw + (size_t)(n0 + 128 + bpr) * KDIM + cg;
    const u16* pB11 = Bw + (size_t)(n0 + 192 + bpr) * KDIM + cg;

// LDS (u16 units): buf b at b*32768; A0 @0, A1 @8192, B0 @16384, B1 @24576.
// granule ins0 dest = half + tid*8, ins1 dest = half + 4096 + tid*8.
// KOFF in u16 elements (= T*64 for K-tile T).
#define STG(P0, P1, BUFU, HALFU, KOFF) \
    gload16(P0 + (KOFF), lds + (BUFU) + (HALFU) + tid * 8); \
    gload16(P1 + (KOFF), lds + (BUFU) + (HALFU) + 4096 + tid * 8);
#define STG_A0(T)  STG(pA00, pA01, 0, 0, (T)*64)
#define STG_A1(T)  STG(pA10, pA11, 0, 8192, (T)*64)
#define STG_B0(T)  STG(pB00, pB01, 0, 16384, (T)*64)
#define STG_B1(T)  STG(pB10, pB11, 0, 24576, (T)*64)
#define STG_A0b(T) STG(pA00, pA01, 32768, 0, (T)*64)
#define STG_A1b(T) STG(pA10, pA11, 32768, 8192, (T)*64)
#define STG_B0b(T) STG(pB00, pB01, 32768, 16384, (T)*64)
#define STG_B1b(T) STG(pB10, pB11, 32768, 24576, (T)*64)

    // ---------------- fragment read bases ----------------
    const char* ldsc = (const char*)lds;
    const int aBase = wm * 16384;                                   // bytes
    const int bBase = 32768 + (wn >> 1) * 16384 + (wn & 1) * 8192;  // bytes
    const int cx = (c & 7) << 4;
    const int kq0 = (quad * 16) ^ cx;
    const int kq1 = (64 + quad * 16) ^ cx;

    short8 af[4][2];
    short8 bf[2][2][2];
    floatx4 acc[8][4];
#pragma unroll
    for (int mf = 0; mf < 8; mf++)
#pragma unroll
        for (int nf = 0; nf < 4; nf++)
            acc[mf][nf] = (floatx4){0.f, 0.f, 0.f, 0.f};

#define LDA(BUF, MH) { _Pragma("unroll") for (int mi = 0; mi < 4; mi++) { \
        const char* pp_ = ldsc + (BUF)*65536 + aBase + (MH)*8192 + (mi*16 + c)*128; \
        af[mi][0] = *(const short8*)(pp_ + kq0); \
        af[mi][1] = *(const short8*)(pp_ + kq1); } }
#define LDB(BUF, NH) { _Pragma("unroll") for (int ni = 0; ni < 2; ni++) { \
        const char* pp_ = ldsc + (BUF)*65536 + bBase + (NH)*4096 + (ni*16 + c)*128; \
        bf[NH][ni][0] = *(const short8*)(pp_ + kq0); \
        bf[NH][ni][1] = *(const short8*)(pp_ + kq1); } }
#define BAR __builtin_amdgcn_s_barrier()
#define WAITLGKM { asm volatile("s_waitcnt lgkmcnt(0)" ::: "memory"); __builtin_amdgcn_sched_barrier(0); }
#define MQ(MH, NH) do { __builtin_amdgcn_s_setprio(1); \
    _Pragma("unroll") for (int kk = 0; kk < 2; kk++) \
    _Pragma("unroll") for (int mi = 0; mi < 4; mi++) \
    _Pragma("unroll") for (int ni = 0; ni < 2; ni++) \
        acc[(MH)*4 + mi][(NH)*2 + ni] = __builtin_amdgcn_mfma_f32_16x16x32_bf16( \
            af[mi][kk], bf[NH][ni][kk], acc[(MH)*4 + mi][(NH)*2 + ni], 0, 0, 0); \
    __builtin_amdgcn_s_setprio(0); } while (0)

// one iteration: compute tiles T (buf0, ph1-4) and T+1 (buf1, ph5-8),
// stage T2 -> buf0 (ph3,4,4,5), T3 -> buf1 (ph7,8,8,8). vmcnt at ph4/ph8.
#define GITER(T2, T3, ST, VM4) \
    /*ph1*/ LDA(0,0); LDB(0,0);                               BAR; WAITLGKM; MQ(0,0); BAR; \
    /*ph2*/ LDB(0,1);                                         BAR; WAITLGKM; MQ(0,1); BAR; \
    /*ph3*/ LDA(0,1); if (ST) { STG_B0(T2); }                 BAR; WAITLGKM; MQ(1,0); BAR; \
    /*ph4*/ if (ST) { STG_B1(T2); STG_A0(T2); }               BAR; WAITLGKM; MQ(1,1); \
            asm volatile("s_waitcnt " VM4 ::: "memory");      BAR; \
    /*ph5*/ LDA(1,0); LDB(1,0); if (ST) { STG_A1(T2); }       BAR; WAITLGKM; MQ(0,0); BAR; \
    /*ph6*/ LDB(1,1);                                         BAR; WAITLGKM; MQ(0,1); BAR; \
    /*ph7*/ LDA(1,1); if (ST) { STG_B0b(T3); }                BAR; WAITLGKM; MQ(1,0); BAR; \
    /*ph8*/ if (ST) { STG_B1b(T3); STG_A0b(T3); STG_A1b(T3); } BAR; WAITLGKM; MQ(1,1); \
            if (ST) { asm volatile("s_waitcnt vmcnt(8)" ::: "memory"); } BAR;

    // prologue: stage tiles 0 (buf0) and 1 (buf1); wait tile0 landed
    STG_A0(0); STG_A1(0); STG_B0(0); STG_B1(0);
    STG_A0b(1); STG_A1b(1); STG_B0b(1); STG_B1b(1);
    asm volatile("s_waitcnt vmcnt(8)" ::: "memory");
    BAR;

    GITER(2, 3, 1, "vmcnt(6)")
    GITER(4, 5, 1, "vmcnt(6)")
    GITER(6, 7, 1, "vmcnt(6)")
    GITER(8, 9, 0, "vmcnt(0)")

    // ---------------- epilogue: bias + bf16, dwordx2 stores ----------------
    // lane covers cols n0 + wn*64 + c*4 + {0,1,2,3} (B perm made nf contiguous)
    const float4 bb = *(const float4*)&bias[n0 + wn * 64 + c * 4];
    u16* cbase = C + (size_t)(m0 + wm * 128 + quad * 4) * NOUT + n0 + wn * 64 + c * 4;
#pragma unroll
    for (int mf = 0; mf < 8; mf++) {
#pragma unroll
        for (int r = 0; r < 4; r++) {
            float x0 = acc[mf][0][r] + bb.x;
            float x1 = acc[mf][1][r] + bb.y;
            float x2 = acc[mf][2][r] + bb.z;
            float x3 = acc[mf][3][r] + bb.w;
            unsigned int d0, d1;
            asm("v_cvt_pk_bf16_f32 %0, %1, %2" : "=v"(d0) : "v"(x0), "v"(x1));
            asm("v_cvt_pk_bf16_f32 %0, %1, %2" : "=v"(d1) : "v"(x2), "v"(x3));
            uint2v w2 = { d0, d1 };
            *(uint2v*)(cbase + (size_t)(mf * 16 + r) * NOUT) = w2;
        }
    }
#undef STG
#undef STG_A0
#undef STG_A1
#undef STG_B0
#undef STG_B1
#undef STG_A0b
#undef STG_A1b
#undef STG_B0b
#undef STG_B1b
#undef LDA
#undef LDB
#undef BAR
#undef WAITLGKM
#undef MQ
#undef GITER
}

// ---------------- attention: MFMA, one wave per (window b, head h) -----------
__global__ __launch_bounds__(256, 3)
void k_attn(const u16* __restrict__ qkv, const float* __restrict__ bmT,
            float* __restrict__ out) {
    __shared__ __align__(16) char smem[4 * 12288];  // per wave: V 4KB + P 8KB
    const int lane = threadIdx.x & 63;
    const int wave = threadIdx.x >> 6;
    const int task = blockIdx.x * 4 + wave;  // 0..32767
    const int b = task >> 4;
    const int h = task & 15;
    const int c = lane & 15;
    const int quad = lane >> 4;
    char* Vs = smem + wave * 12288;
    char* Ps = Vs + 4096;

    const u16* qbase = qkv + (size_t)b * NTOK * NOUT + h * 32;

    // ---- Q/K fragments direct from global (A/B frag = 16 contiguous bytes) ----
    short8 kf[4], qf[4];
#pragma unroll
    for (int mi = 0; mi < 4; mi++) {
        int jr = mi * 16 + c; jr = jr > 48 ? 48 : jr;
        kf[mi] = *(const short8*)(qbase + (size_t)jr * NOUT + 512 + quad * 8);
    }
#pragma unroll
    for (int ni = 0; ni < 4; ni++) {
        int ir = ni * 16 + c; ir = ir > 48 ? 48 : ir;
        qf[ni] = *(const short8*)(qbase + (size_t)ir * NOUT + quad * 8);
    }

    // ---- stage V -> LDS bf16 [64 rows][32 d], 16B-slot swizzle, pad rows = 0 ----
#pragma unroll
    for (int it = 0; it < 4; it++) {
        int j = it * 16 + (lane >> 2);
        int part = lane & 3;
        ushort8v val = {0, 0, 0, 0, 0, 0, 0, 0};
        if (j < 49) val = *(const ushort8v*)(qbase + (size_t)j * NOUT + 1024 + part * 8);
        int byt = (j * 64 + part * 16) ^ (((j >> 3) & 3) << 4);
        *(ushort8v*)(Vs + byt) = val;
    }

    // ---- S^T = K @ Q^T: acc[mi][ni], row j = mi*16+quad*4+r, col i = ni*16+c ----
    floatx4 acc[4][4];
#pragma unroll
    for (int mi = 0; mi < 4; mi++)
#pragma unroll
        for (int ni = 0; ni < 4; ni++)
            acc[mi][ni] = (floatx4){0.f, 0.f, 0.f, 0.f};
#pragma unroll
    for (int mi = 0; mi < 4; mi++)
#pragma unroll
        for (int ni = 0; ni < 4; ni++)
            acc[mi][ni] = __builtin_amdgcn_mfma_f32_16x16x32_bf16(kf[mi], qf[ni], acc[mi][ni], 0, 0, 0);

    // ---- scale + (bias+mask), key-major table: bmT[.. + j*49 + i] ----
    const float scale = 0.17677669529663687f;
    const float* bmrow = bmT + ((size_t)((b & 63) * 16 + h)) * 2401;
#pragma unroll
    for (int mi = 0; mi < 4; mi++)
#pragma unroll
        for (int r = 0; r < 4; r++) {
            int j = mi * 16 + quad * 4 + r;
            int jc = j > 48 ? 48 : j;
            const float* bp = bmrow + jc * 49;
#pragma unroll
            for (int ni = 0; ni < 4; ni++) {
                int i = ni * 16 + c;
                int ic = i > 48 ? 48 : i;
                acc[mi][ni][r] = acc[mi][ni][r] * scale + bp[ic];
            }
        }

    // ---- softmax over j per column i: in-lane 13 valid + shfl_xor(16,32) ----
#pragma unroll
    for (int ni = 0; ni < 4; ni++) {
        float mx = -3.0e38f;
#pragma unroll
        for (int mi = 0; mi < 3; mi++)
#pragma unroll
            for (int r = 0; r < 4; r++) mx = fmaxf(mx, acc[mi][ni][r]);
        if (quad == 0) mx = fmaxf(mx, acc[3][ni][0]);   // j == 48
        mx = fmaxf(mx, __shfl_xor(mx, 16));
        mx = fmaxf(mx, __shfl_xor(mx, 32));
        float sum = 0.f;
#pragma unroll
        for (int mi = 0; mi < 3; mi++)
#pragma unroll
            for (int r = 0; r < 4; r++) {
                float e = __expf(acc[mi][ni][r] - mx);
                acc[mi][ni][r] = e; sum += e;
            }
        float e0 = (quad == 0) ? __expf(acc[3][ni][0] - mx) : 0.f;
        acc[3][ni][0] = e0; sum += e0;
        acc[3][ni][1] = 0.f; acc[3][ni][2] = 0.f; acc[3][ni][3] = 0.f;
        sum += __shfl_xor(sum, 16);
        sum += __shfl_xor(sum, 32);
        float inv = 1.0f / sum;
#pragma unroll
        for (int mi = 0; mi < 4; mi++)
#pragma unroll
            for (int r = 0; r < 4; r++) acc[mi][ni][r] *= inv;
    }

    // ---- write P[i][j] bf16 to LDS, byte(i,j) = i*128 + (j*2 ^ ((i&7)<<4)) ----
    const int cx = (c & 7) << 4;
#pragma unroll
    for (int ni = 0; ni < 4; ni++) {
        char* prow = Ps + (ni * 16 + c) * 128;
#pragma unroll
        for (int mi = 0; mi < 4; mi++) {
            unsigned int d0, d1;
            asm("v_cvt_pk_bf16_f32 %0, %1, %2" : "=v"(d0) : "v"(acc[mi][ni][0]), "v"(acc[mi][ni][1]));
            asm("v_cvt_pk_bf16_f32 %0, %1, %2" : "=v"(d1) : "v"(acc[mi][ni][2]), "v"(acc[mi][ni][3]));
            uint2v w2 = { d0, d1 };
            *(uint2v*)(prow + ((mi * 32 + quad * 8) ^ cx)) = w2;
        }
    }

    // ---- make all LDS writes (V stage + P) visible to this wave's reads ----
    asm volatile("s_waitcnt lgkmcnt(0)" ::: "memory");

    // ---- ctx = P @ V: A-frag = P rows (swizzled b128), B-frag = V cols ----
    floatx4 acc2[4][2];
#pragma unroll
    for (int mi = 0; mi < 4; mi++)
#pragma unroll
        for (int ni = 0; ni < 2; ni++) acc2[mi][ni] = (floatx4){0.f, 0.f, 0.f, 0.f};
    const int vb0 = quad * 512 + (((0 * 16 + c) * 2) ^ (quad << 4));
    const int vb1 = quad * 512 + (((1 * 16 + c) * 2) ^ (quad << 4));
#pragma unroll
    for (int kk = 0; kk < 2; kk++) {
        const int plow = (kk * 64 + quad * 16) ^ cx;
        short8 pf[4];
#pragma unroll
        for (int mi = 0; mi < 4; mi++)
            pf[mi] = *(const short8*)(Ps + mi * 2048 + c * 128 + plow);
        short8 vf[2];
#pragma unroll
        for (int ni = 0; ni < 2; ni++) {
            const char* vbp = Vs + (ni ? vb1 : vb0) + kk * 2048;
#pragma unroll
            for (int z = 0; z < 8; z++)
                vf[ni][z] = *(const short*)(vbp + z * 64);
        }
#pragma unroll
        for (int mi = 0; mi < 4; mi++)
#pragma unroll
            for (int ni = 0; ni < 2; ni++)
                acc2[mi][ni] = __builtin_amdgcn_mfma_f32_16x16x32_bf16(pf[mi], vf[ni], acc2[mi][ni], 0, 0, 0);
    }

    // ---- store: D row = i = mi*16+quad*4+r, col = d = ni*16+c (fp32 out) ----
    float* ob = out + (size_t)b * 49 * CDIM + h * 32;
#pragma unroll
    for (int mi = 0; mi < 4; mi++)
#pragma unroll
        for (int r = 0; r < 4; r++) {
            int i = mi * 16 + quad * 4 + r;
            if (i < 49) {
                float* orow = ob + (size_t)i * CDIM + c;
#pragma unroll
                for (int ni = 0; ni < 2; ni++)
                    orow[ni * 16] = acc2[mi][ni][r];
            }
        }
}

extern "C" void kernel_launch(void* const* d_in, const int* in_sizes, int n_in,
                              void* d_out, int out_size, void* d_ws, size_t ws_size,
                              hipStream_t stream) {
    const float* hs   = (const float*)d_in[0];
    const float* mask = (const float*)d_in[1];
    const float* wq   = (const float*)d_in[2];
    const float* bq   = (const float*)d_in[3];
    const float* wk   = (const float*)d_in[4];
    const float* bk   = (const float*)d_in[5];
    const float* wv   = (const float*)d_in[6];
    const float* bv   = (const float*)d_in[7];
    const float* bt   = (const float*)d_in[8];
    float* out = (float*)d_out;

    char* ws = (char*)d_ws;
    size_t off = 0;
    u16* xb = (u16*)(ws + off);      off += (size_t)MTOT * CDIM * 2;       // 102.8 MB
    u16* wb = (u16*)(ws + off);      off += (size_t)NOUT * KDIM * 2;       // 1.5 MB
    float* biasb = (float*)(ws + off); off += (size_t)NOUT * 4;
    off = (off + 255) & ~(size_t)255;
    float* bm = (float*)(ws + off);  off += (size_t)1024 * 2401 * 4;       // 9.8 MB
    off = (off + 255) & ~(size_t)255;
    u16* qkv = (u16*)(ws + off);     off += (size_t)MTOT * NOUT * 2;       // 308 MB

    k_cvt_x<<<4096, 256, 0, stream>>>((const float4*)hs, (ushort4v*)xb, MTOT * CDIM / 4);
    k_pack_w<<<3072, 256, 0, stream>>>(wq, wk, wv, bq, bk, bv, wb, biasb);
    k_bm<<<1024, 256, 0, stream>>>(mask, bt, bm);
    k_gemm256<<<2352, 512, 0, stream>>>(xb, wb, biasb, qkv);
    k_attn<<<8192, 256, 0, stream>>>(qkv, bm, out);
}